// Round 1
// baseline (212.682 us; speedup 1.0000x reference)
//
#include <hip/hip_runtime.h>
#include <hip/hip_bf16.h>
#include <math.h>

#define MTOK 16384
#define DDIM 2048
#define NEXP 8
#define RNK 16
#define NC 128          // E*R down-projection columns
#define NW 160          // padded GEMM1 N: 128 h + 8 logits + 24 zero pad
#define LOGIT0 128

typedef __attribute__((ext_vector_type(8))) short bf16x8;
typedef __attribute__((ext_vector_type(4))) short short4v;
typedef __attribute__((ext_vector_type(4))) float f32x4;

__device__ __forceinline__ short f2b(float f) {
  unsigned u = __float_as_uint(f);
  u += 0x7fffu + ((u >> 16) & 1u);   // round-to-nearest-even
  return (short)(u >> 16);
}

// ---------------- K0: weight prep (fp32 -> bf16, transposed layouts) -------
// WdT[n][d], n in [0,160): n<128 -> down[e=n>>4][d][r=n&15]; 128..135 -> router_w[n-128][d]; else 0
// UT[d][c],  c in [0,128): up[e=c>>4][r=c&15][d]
__global__ __launch_bounds__(256) void prep_k(const float* __restrict__ rw,
                                              const float* __restrict__ down,
                                              const float* __restrict__ up,
                                              short* __restrict__ WdT,
                                              short* __restrict__ UT) {
  int i = blockIdx.x * 256 + threadIdx.x;
  const int NWD = NW * DDIM;          // 327680
  const int NUT = DDIM * NC;          // 262144
  if (i < NWD) {
    int n = i / DDIM, d = i % DDIM;
    float v = 0.f;
    if (n < NC)            v = down[((n >> 4) * DDIM + d) * RNK + (n & 15)];
    else if (n < NC + NEXP) v = rw[(n - NC) * DDIM + d];
    WdT[i] = f2b(v);
  } else if (i < NWD + NUT) {
    int u = i - NWD;
    int d = u >> 7, c = u & 127;
    UT[u] = f2b(up[((c >> 4) * RNK + (c & 15)) * DDIM + d]);
  }
}

// ---------------- K1: GEMM1  H[16384][160] = X(bf16) @ WdT^T ---------------
// BM=64, BK=64, full N=160. 4 waves: 2(row)x2(col) split, each 32 rows x 80 cols.
__global__ __launch_bounds__(256) void gemm1_k(const float* __restrict__ X,
                                               const short* __restrict__ WdT,
                                               float* __restrict__ H) {
  __shared__ short Al[64][72];     // +8 pad: row stride 144B -> ~2-way banks
  __shared__ short Bl[NW][72];
  const int tid = threadIdx.x;
  const int lane = tid & 63;
  const int w = tid >> 6;
  const int gm0 = blockIdx.x * 64;
  const int wr = (w & 1) * 32;     // wave row base
  const int wc = (w >> 1) * 80;    // wave col base (5 frags of 16)
  const int lr = lane & 15;
  const int lk = (lane >> 4) * 8;

  f32x4 acc[2][5];
#pragma unroll
  for (int m = 0; m < 2; ++m)
#pragma unroll
    for (int n = 0; n < 5; ++n) acc[m][n] = (f32x4){0.f, 0.f, 0.f, 0.f};

  float4 aR[4];   // A staging regs: 64x64 fp32 = 256 thr * 4 * float4
  uint4  bR[5];   // B staging regs: 160x64 bf16 = 256 thr * 5 * 16B

  auto loadRegs = [&](int kt) {
    const int k0 = kt * 64;
#pragma unroll
    for (int i = 0; i < 4; ++i) {
      int f = tid + 256 * i;
      int row = f >> 4, c4 = f & 15;
      aR[i] = *(const float4*)(X + (size_t)(gm0 + row) * DDIM + k0 + c4 * 4);
    }
#pragma unroll
    for (int i = 0; i < 5; ++i) {
      int f = tid + 256 * i;
      int row = f >> 3, c8 = f & 7;
      bR[i] = *(const uint4*)(WdT + (size_t)row * DDIM + k0 + c8 * 8);
    }
  };
  auto writeRegs = [&]() {
#pragma unroll
    for (int i = 0; i < 4; ++i) {
      int f = tid + 256 * i;
      int row = f >> 4, c4 = f & 15;
      short4v v;
      v.x = f2b(aR[i].x); v.y = f2b(aR[i].y); v.z = f2b(aR[i].z); v.w = f2b(aR[i].w);
      *(short4v*)&Al[row][c4 * 4] = v;
    }
#pragma unroll
    for (int i = 0; i < 5; ++i) {
      int f = tid + 256 * i;
      int row = f >> 3, c8 = f & 7;
      *(uint4*)&Bl[row][c8 * 8] = bR[i];
    }
  };
  auto compute = [&]() {
#pragma unroll
    for (int kk = 0; kk < 64; kk += 32) {
      bf16x8 a[2], b[5];
#pragma unroll
      for (int m = 0; m < 2; ++m) a[m] = *(const bf16x8*)&Al[wr + m * 16 + lr][kk + lk];
#pragma unroll
      for (int n = 0; n < 5; ++n) b[n] = *(const bf16x8*)&Bl[wc + n * 16 + lr][kk + lk];
#pragma unroll
      for (int m = 0; m < 2; ++m)
#pragma unroll
        for (int n = 0; n < 5; ++n)
          acc[m][n] = __builtin_amdgcn_mfma_f32_16x16x32_bf16(a[m], b[n], acc[m][n], 0, 0, 0);
    }
  };

  loadRegs(0);
  writeRegs();
  __syncthreads();
  for (int kt = 0; kt < 32; ++kt) {
    if (kt + 1 < 32) loadRegs(kt + 1);   // prefetch next tile into regs
    compute();
    __syncthreads();
    if (kt + 1 < 32) writeRegs();
    __syncthreads();
  }

  const int cr = (lane >> 4) * 4;
#pragma unroll
  for (int m = 0; m < 2; ++m)
#pragma unroll
    for (int n = 0; n < 5; ++n)
#pragma unroll
      for (int r = 0; r < 4; ++r) {
        int row = gm0 + wr + m * 16 + cr + r;
        int col = wc + n * 16 + lr;
        H[(size_t)row * NW + col] = acc[m][n][r];
      }
}

// ---------------- K2: routing — top2 + softmax + scale -> Hw bf16 ----------
__global__ __launch_bounds__(256) void route_k(const float* __restrict__ H,
                                               short* __restrict__ Hw) {
  __shared__ float w0s[64], w1s[64];
  __shared__ int e0s[64], e1s[64];
  const int tid = threadIdx.x;
  const int t0 = blockIdx.x * 64;
  if (tid < 64) {
    const float* lg = H + (size_t)(t0 + tid) * NW + LOGIT0;
    float b0 = -1e30f, b1 = -1e30f;
    int i0 = 0, i1 = 0;
#pragma unroll
    for (int e = 0; e < 8; ++e) {
      float v = lg[e];
      if (v > b0) { b1 = b0; i1 = i0; b0 = v; i0 = e; }   // strict > : lax.top_k tie-break (low idx first)
      else if (v > b1) { b1 = v; i1 = e; }
    }
    float ex = __expf(b1 - b0);
    float inv = 1.f / (1.f + ex);
    w0s[tid] = inv; w1s[tid] = ex * inv;
    e0s[tid] = i0; e1s[tid] = i1;
  }
  __syncthreads();
#pragma unroll
  for (int i = 0; i < 32; ++i) {
    int f = tid + 256 * i;         // 64 tokens x 128 cols
    int t = f >> 7, c = f & 127;
    float v = H[(size_t)(t0 + t) * NW + c];
    int e = c >> 4;
    float wgt = (e == e0s[t]) ? w0s[t] : ((e == e1s[t]) ? w1s[t] : 0.f);
    Hw[(size_t)(t0 + t) * NC + c] = f2b(v * wgt);
  }
}

// ---------------- K3: GEMM2 + residual  Out = X + Hw @ U -------------------
// BM=128, BN=64, K=128 (single stage). 4 waves each: 32 rows x 64 cols.
__global__ __launch_bounds__(256) void gemm2_k(const short* __restrict__ Hw,
                                               const short* __restrict__ UT,
                                               const float* __restrict__ X,
                                               float* __restrict__ Out) {
  __shared__ short Al[128][136];   // +8 pad, row stride 272B
  __shared__ short Bl[64][136];
  const int tid = threadIdx.x;
  const int lane = tid & 63;
  const int w = tid >> 6;
  const int gm0 = blockIdx.x * 128;
  const int n0 = blockIdx.y * 64;
  const int lr = lane & 15;
  const int lk = (lane >> 4) * 8;

#pragma unroll
  for (int i = 0; i < 8; ++i) {
    int f = tid + 256 * i;         // 128 rows x 16 chunks(16B)
    int row = f >> 4, c8 = f & 15;
    *(uint4*)&Al[row][c8 * 8] = *(const uint4*)(Hw + (size_t)(gm0 + row) * NC + c8 * 8);
  }
#pragma unroll
  for (int i = 0; i < 4; ++i) {
    int f = tid + 256 * i;         // 64 rows x 16 chunks
    int row = f >> 4, c8 = f & 15;
    *(uint4*)&Bl[row][c8 * 8] = *(const uint4*)(UT + (size_t)(n0 + row) * NC + c8 * 8);
  }
  __syncthreads();

  f32x4 acc[2][4];
#pragma unroll
  for (int m = 0; m < 2; ++m)
#pragma unroll
    for (int n = 0; n < 4; ++n) acc[m][n] = (f32x4){0.f, 0.f, 0.f, 0.f};

#pragma unroll
  for (int ks = 0; ks < 4; ++ks) {
    const int kk = ks * 32;
    bf16x8 a[2], b[4];
#pragma unroll
    for (int m = 0; m < 2; ++m) a[m] = *(const bf16x8*)&Al[w * 32 + m * 16 + lr][kk + lk];
#pragma unroll
    for (int n = 0; n < 4; ++n) b[n] = *(const bf16x8*)&Bl[n * 16 + lr][kk + lk];
#pragma unroll
    for (int m = 0; m < 2; ++m)
#pragma unroll
      for (int n = 0; n < 4; ++n)
        acc[m][n] = __builtin_amdgcn_mfma_f32_16x16x32_bf16(a[m], b[n], acc[m][n], 0, 0, 0);
  }

  const int cr = (lane >> 4) * 4;
#pragma unroll
  for (int m = 0; m < 2; ++m)
#pragma unroll
    for (int n = 0; n < 4; ++n)
#pragma unroll
      for (int r = 0; r < 4; ++r) {
        int row = gm0 + w * 32 + m * 16 + cr + r;
        int col = n0 + n * 16 + lr;
        size_t idx = (size_t)row * DDIM + col;
        Out[idx] = X[idx] + acc[m][n][r];
      }
}

// ---------------------------------------------------------------------------
extern "C" void kernel_launch(void* const* d_in, const int* in_sizes, int n_in,
                              void* d_out, int out_size, void* d_ws, size_t ws_size,
                              hipStream_t stream) {
  const float* x    = (const float*)d_in[0];
  const float* rw   = (const float*)d_in[1];
  const float* down = (const float*)d_in[2];
  const float* up   = (const float*)d_in[3];
  float* out = (float*)d_out;

  char* ws = (char*)d_ws;
  short* WdT = (short*)ws;                                   // 160*2048*2   = 655360 B
  short* UT  = (short*)(ws + 655360);                        // 2048*128*2   = 524288 B
  float* H   = (float*)(ws + 655360 + 524288);               // 16384*160*4  = 10485760 B
  short* Hw  = (short*)(ws + 655360 + 524288 + 10485760);    // 16384*128*2  = 4194304 B

  prep_k<<<2304, 256, 0, stream>>>(rw, down, up, WdT, UT);           // (327680+262144)/256
  gemm1_k<<<MTOK / 64, 256, 0, stream>>>(x, WdT, H);                 // 256 blocks
  route_k<<<MTOK / 64, 256, 0, stream>>>(H, Hw);                     // 256 blocks
  gemm2_k<<<dim3(MTOK / 128, DDIM / 64), 256, 0, stream>>>(Hw, UT, x, out);  // 128x32
}

// Round 2
// 92.354 us; speedup vs baseline: 2.3029x; 2.3029x over previous
//
#include <hip/hip_runtime.h>
#include <hip/hip_bf16.h>

#define MTOK 16384
#define DDIM 2048
#define NEXP 8
#define RNK 16
#define NC 128          // E*R down-projection columns
#define NW 160          // padded GEMM1 N: 128 h + 8 logits + 24 zero pad
#define LOGIT0 128
#define KSPLIT 2
#define KLEN (DDIM / KSPLIT)   // 1024
#define NT (KLEN / 64)         // 16 K-steps of 64

typedef __attribute__((ext_vector_type(8))) short bf16x8;
typedef __attribute__((ext_vector_type(4))) short short4v;
typedef __attribute__((ext_vector_type(4))) float f32x4;

typedef __attribute__((address_space(1))) const void gv_t;
typedef __attribute__((address_space(3))) void lv_t;

__device__ __forceinline__ short f2b(float f) {
  unsigned u = __float_as_uint(f);
  u += 0x7fffu + ((u >> 16) & 1u);   // round-to-nearest-even
  return (short)(u >> 16);
}
__device__ __forceinline__ float b2f(short s) {
  return __uint_as_float(((unsigned)(unsigned short)s) << 16);
}

// ---------------- K0: weight prep (fp32 -> bf16, transposed layouts) -------
// WdT is stored PRE-SWIZZLED per 64-elem K-tile: within each tile, the 16B
// slot index s (0..7) at linear position holds logical slot s^(n&7), so that
// gemm1's linear global_load_lds produces an XOR-swizzled LDS tile and the
// swizzled ds_read_b128 is bank-conflict-free (T2 via pre-swizzled source).
// Logical WdT[n][k]: n<128 -> down[n>>4][k][n&15]; 128..135 -> rw[n-128][k]; else 0
// UT[d][c] (unswizzled): up[c>>4][c&15][d]
__global__ __launch_bounds__(256) void prep_k(const float* __restrict__ rw,
                                              const float* __restrict__ down,
                                              const float* __restrict__ up,
                                              short* __restrict__ WdT,
                                              short* __restrict__ UT) {
  int i = blockIdx.x * 256 + threadIdx.x;
  const int NWD = NW * DDIM;          // 327680
  const int NUT = DDIM * NC;          // 262144
  if (i < NWD) {
    int n = i / DDIM, k = i % DDIM;
    int s = (k >> 3) & 7;
    int src_k = (k & ~0x3F) | ((s ^ (n & 7)) << 3) | (k & 7);
    float v = 0.f;
    if (n < NC)             v = down[((n >> 4) * DDIM + src_k) * RNK + (n & 15)];
    else if (n < NC + NEXP) v = rw[(n - NC) * DDIM + src_k];
    WdT[i] = f2b(v);
  } else if (i < NWD + NUT) {
    int u = i - NWD;
    int d = u >> 7, c = u & 127;
    UT[u] = f2b(up[((c >> 4) * RNK + (c & 15)) * DDIM + d]);
  }
}

// ---------------- K1: GEMM1  Hp[ks][16384][160] (bf16) = X @ WdT^T ---------
// Split-K=2, BM=64, BK=64. 4 waves: 2(row)x2(col), each 32 rows x 80 cols.
// B: global_load_lds (16B) into linear double-buffered LDS (pre-swizzled src).
// A: reg-staged fp32 -> bf16 into padded LDS. One barrier per K-step.
__global__ __launch_bounds__(256, 2) void gemm1_k(const float* __restrict__ X,
                                                  const short* __restrict__ WdT,
                                                  short* __restrict__ Hp) {
  __shared__ short Al[2][64][72];      // 18432 B (+8 pad: stride 144B, ~2-way)
  __shared__ short Bl[2][160 * 64];    // 40960 B, linear for global_load_lds
  const int tid = threadIdx.x;
  const int lane = tid & 63;
  const int w = tid >> 6;
  const int gm0 = blockIdx.x * 64;
  const int ks = blockIdx.y;
  const int kb = ks * KLEN;
  const int wr = (w & 1) * 32;         // wave row base
  const int wc = (w >> 1) * 80;        // wave col base (5 frags of 16)
  const int lr = lane & 15;
  const int lk = (lane >> 4) * 8;

  f32x4 acc[2][5];
#pragma unroll
  for (int m = 0; m < 2; ++m)
#pragma unroll
    for (int n = 0; n < 5; ++n) acc[m][n] = (f32x4){0.f, 0.f, 0.f, 0.f};

  float4 aR[4];   // A staging: 64x64 fp32 = 256 thr * 4 * float4

  auto loadA = [&](int k0) {
#pragma unroll
    for (int i2 = 0; i2 < 4; ++i2) {
      int f = tid + 256 * i2;
      int row = f >> 4, c4 = f & 15;
      aR[i2] = *(const float4*)(X + (size_t)(gm0 + row) * DDIM + k0 + c4 * 4);
    }
  };
  auto issueB = [&](int buf, int k0) {
    // 160x64 bf16 = 1280 x 16B units; 4 waves x 5 calls x 64 lanes
#pragma unroll
    for (int j = 0; j < 5; ++j) {
      int u = (w * 5 + j) * 64 + lane;          // unit index
      const short* g = WdT + (size_t)(u >> 3) * DDIM + k0 + (u & 7) * 8;
      short* l = &Bl[buf][(w * 5 + j) * 512];   // wave-uniform base
      __builtin_amdgcn_global_load_lds((gv_t*)g, (lv_t*)l, 16, 0, 0);
    }
  };
  auto writeA = [&](int buf) {
#pragma unroll
    for (int i2 = 0; i2 < 4; ++i2) {
      int f = tid + 256 * i2;
      int row = f >> 4, c4 = f & 15;
      short4v v;
      v.x = f2b(aR[i2].x); v.y = f2b(aR[i2].y);
      v.z = f2b(aR[i2].z); v.w = f2b(aR[i2].w);
      *(short4v*)&Al[buf][row][c4 * 4] = v;
    }
  };
  auto compute = [&](int buf) {
#pragma unroll
    for (int kk2 = 0; kk2 < 2; ++kk2) {
      const int kk = kk2 * 32;
      bf16x8 a[2], b[5];
#pragma unroll
      for (int m = 0; m < 2; ++m)
        a[m] = *(const bf16x8*)&Al[buf][wr + m * 16 + lr][kk + lk];
#pragma unroll
      for (int n = 0; n < 5; ++n) {
        int row = wc + n * 16 + lr;
        int sl = ((kk >> 3) + (lane >> 4)) ^ (row & 7);   // swizzled 16B slot
        b[n] = *(const bf16x8*)&Bl[buf][row * 64 + sl * 8];
      }
#pragma unroll
      for (int m = 0; m < 2; ++m)
#pragma unroll
        for (int n = 0; n < 5; ++n)
          acc[m][n] = __builtin_amdgcn_mfma_f32_16x16x32_bf16(a[m], b[n], acc[m][n], 0, 0, 0);
    }
  };

  loadA(kb);
  issueB(0, kb);
  writeA(0);
  __syncthreads();
  for (int t = 0; t < NT; ++t) {
    const int cur = t & 1, nxt = cur ^ 1;
    if (t + 1 < NT) {
      loadA(kb + (t + 1) * 64);
      issueB(nxt, kb + (t + 1) * 64);
    }
    compute(cur);
    if (t + 1 < NT) writeA(nxt);
    __syncthreads();
  }

  short* Hq = Hp + (size_t)ks * MTOK * NW;
  const int cr = (lane >> 4) * 4;
#pragma unroll
  for (int m = 0; m < 2; ++m)
#pragma unroll
    for (int n = 0; n < 5; ++n)
#pragma unroll
      for (int r = 0; r < 4; ++r) {
        int row = gm0 + wr + m * 16 + cr + r;
        int col = wc + n * 16 + lr;
        Hq[(size_t)row * NW + col] = f2b(acc[m][n][r]);
      }
}

// ---------------- K2: routing — sum split-K, top2 softmax, scale -> Hw -----
__global__ __launch_bounds__(256) void route_k(const short* __restrict__ Hp,
                                               short* __restrict__ Hw) {
  __shared__ float wv[64][8];
  const int tid = threadIdx.x;
  const int t0 = blockIdx.x * 64;
  const short* H0 = Hp;
  const short* H1 = Hp + (size_t)MTOK * NW;
  if (tid < 64) {
    int t = t0 + tid;
    uint4 l0 = *(const uint4*)(H0 + (size_t)t * NW + LOGIT0);
    uint4 l1 = *(const uint4*)(H1 + (size_t)t * NW + LOGIT0);
    const short* p0 = (const short*)&l0;
    const short* p1 = (const short*)&l1;
    float b0 = -1e30f, b1 = -1e30f;
    int i0 = 0, i1 = 0;
#pragma unroll
    for (int e = 0; e < 8; ++e) {
      float v = b2f(p0[e]) + b2f(p1[e]);
      if (v > b0) { b1 = b0; i1 = i0; b0 = v; i0 = e; }   // lax.top_k tie-break
      else if (v > b1) { b1 = v; i1 = e; }
    }
    float ex = __expf(b1 - b0);
    float inv = 1.f / (1.f + ex);
#pragma unroll
    for (int e = 0; e < 8; ++e)
      wv[tid][e] = (e == i0) ? inv : ((e == i1) ? ex * inv : 0.f);
  }
  __syncthreads();
  const int t = tid >> 2, q = tid & 3;     // token, col-quarter (32 cols)
  const short* a0 = H0 + (size_t)(t0 + t) * NW + q * 32;
  const short* a1 = H1 + (size_t)(t0 + t) * NW + q * 32;
  short* o = Hw + (size_t)(t0 + t) * NC + q * 32;
#pragma unroll
  for (int j = 0; j < 4; ++j) {
    uint4 v0 = *(const uint4*)(a0 + j * 8);
    uint4 v1 = *(const uint4*)(a1 + j * 8);
    const short* s0 = (const short*)&v0;
    const short* s1 = (const short*)&v1;
    short r[8];
    int cbase = q * 32 + j * 8;
#pragma unroll
    for (int e2 = 0; e2 < 8; ++e2) {
      float h = b2f(s0[e2]) + b2f(s1[e2]);
      r[e2] = f2b(h * wv[t][(cbase + e2) >> 4]);
    }
    *(uint4*)(o + j * 8) = *(uint4*)r;
  }
}

// ---------------- K3: GEMM2 + residual  Out = X + Hw @ U -------------------
// BM=128, BN=64, K=128 (single stage). 4 waves each: 32 rows x 64 cols.
__global__ __launch_bounds__(256) void gemm2_k(const short* __restrict__ Hw,
                                               const short* __restrict__ UT,
                                               const float* __restrict__ X,
                                               float* __restrict__ Out) {
  __shared__ short Al[128][136];   // +8 pad, row stride 272B
  __shared__ short Bl[64][136];
  const int tid = threadIdx.x;
  const int lane = tid & 63;
  const int w = tid >> 6;
  const int gm0 = blockIdx.x * 128;
  const int n0 = blockIdx.y * 64;
  const int lr = lane & 15;
  const int lk = (lane >> 4) * 8;

#pragma unroll
  for (int i = 0; i < 8; ++i) {
    int f = tid + 256 * i;         // 128 rows x 16 chunks(16B)
    int row = f >> 4, c8 = f & 15;
    *(uint4*)&Al[row][c8 * 8] = *(const uint4*)(Hw + (size_t)(gm0 + row) * NC + c8 * 8);
  }
#pragma unroll
  for (int i = 0; i < 4; ++i) {
    int f = tid + 256 * i;         // 64 rows x 16 chunks
    int row = f >> 4, c8 = f & 15;
    *(uint4*)&Bl[row][c8 * 8] = *(const uint4*)(UT + (size_t)(n0 + row) * NC + c8 * 8);
  }
  __syncthreads();

  f32x4 acc[2][4];
#pragma unroll
  for (int m = 0; m < 2; ++m)
#pragma unroll
    for (int n = 0; n < 4; ++n) acc[m][n] = (f32x4){0.f, 0.f, 0.f, 0.f};

#pragma unroll
  for (int ks = 0; ks < 4; ++ks) {
    const int kk = ks * 32;
    bf16x8 a[2], b[4];
#pragma unroll
    for (int m = 0; m < 2; ++m) a[m] = *(const bf16x8*)&Al[w * 32 + m * 16 + lr][kk + lk];
#pragma unroll
    for (int n = 0; n < 4; ++n) b[n] = *(const bf16x8*)&Bl[n * 16 + lr][kk + lk];
#pragma unroll
    for (int m = 0; m < 2; ++m)
#pragma unroll
      for (int n = 0; n < 4; ++n)
        acc[m][n] = __builtin_amdgcn_mfma_f32_16x16x32_bf16(a[m], b[n], acc[m][n], 0, 0, 0);
  }

  const int cr = (lane >> 4) * 4;
#pragma unroll
  for (int m = 0; m < 2; ++m)
#pragma unroll
    for (int n = 0; n < 4; ++n)
#pragma unroll
      for (int r = 0; r < 4; ++r) {
        int row = gm0 + w * 32 + m * 16 + cr + r;
        int col = n0 + n * 16 + lr;
        size_t idx = (size_t)row * DDIM + col;
        Out[idx] = X[idx] + acc[m][n][r];
      }
}

// ---------------------------------------------------------------------------
extern "C" void kernel_launch(void* const* d_in, const int* in_sizes, int n_in,
                              void* d_out, int out_size, void* d_ws, size_t ws_size,
                              hipStream_t stream) {
  const float* x    = (const float*)d_in[0];
  const float* rw   = (const float*)d_in[1];
  const float* down = (const float*)d_in[2];
  const float* up   = (const float*)d_in[3];
  float* out = (float*)d_out;

  char* ws = (char*)d_ws;
  short* WdT = (short*)ws;                          // 160*2048*2          =   655360 B
  short* UT  = (short*)(ws + 655360);               // 2048*128*2          =   524288 B
  short* Hp  = (short*)(ws + 1179648);              // 2*16384*160*2       = 10485760 B
  short* Hw  = (short*)(ws + 11665408);             // 16384*128*2         =  4194304 B
                                                    // total 15859712 B (proven fit)

  prep_k<<<2304, 256, 0, stream>>>(rw, down, up, WdT, UT);
  gemm1_k<<<dim3(MTOK / 64, KSPLIT), 256, 0, stream>>>(x, WdT, Hp);        // 512 blocks
  route_k<<<MTOK / 64, 256, 0, stream>>>(Hp, Hw);                          // 256 blocks
  gemm2_k<<<dim3(MTOK / 128, DDIM / 64), 256, 0, stream>>>(Hw, UT, x, out); // 4096 blocks
}